// Round 1
// 1629.443 us; speedup vs baseline: 1.0632x; 1.0632x over previous
//
#include <hip/hip_runtime.h>

// AxialAttentionBlock: xs (B=8, C=512, H=128, W=128) fp32, 8 heads, dh=64.
// I/O fp32 (per reference); internal compute bf16 MFMA.
// R1: gemm -> global_load_lds (m97 structure); fuse Q/K/V projections (N=1536).
#define CC   512
#define HWT  16384     // H*W
#define NB   8         // batches
#define DH   64
#define SEQ  128
#define C3   1536      // packed QKV pitch

typedef __bf16 bf16_t;
typedef __bf16 bf16x8 __attribute__((ext_vector_type(8)));
typedef float  f32x4  __attribute__((ext_vector_type(4)));

#define GLOAD_LDS16(g, l)                                                      \
  __builtin_amdgcn_global_load_lds(                                            \
      (const __attribute__((address_space(1))) void*)(g),                      \
      (__attribute__((address_space(3))) void*)(l), 16, 0, 0)

// ---------------------------------------------------------------------------
// PREP: 8 weight matrices fp32 (C,C) -> bf16, layout unchanged ([n][k]).
// Slot order q_h,k_h,v_h,o_h,q_w,k_w,v_w,o_w: slots 0-2 and 4-6 form packed
// (1536,512) QKV weights for the fused projection GEMM.
// ---------------------------------------------------------------------------
__global__ __launch_bounds__(256) void prep_w_kernel(const float* __restrict__ W0,
                                                     const float* __restrict__ W1,
                                                     const float* __restrict__ W2,
                                                     const float* __restrict__ W3,
                                                     const float* __restrict__ W4,
                                                     const float* __restrict__ W5,
                                                     const float* __restrict__ W6,
                                                     const float* __restrict__ W7,
                                                     bf16_t* __restrict__ Wb) {
  const float* Wsrc[8] = {W0, W1, W2, W3, W4, W5, W6, W7};
  const int w = blockIdx.y;
  const int i = (blockIdx.x * 256 + threadIdx.x) * 4;      // 512*512 elems per W
  float4 v = *(const float4*)(Wsrc[w] + i);
  bf16_t* o = Wb + (size_t)w * (CC * CC) + i;
  o[0] = (bf16_t)v.x; o[1] = (bf16_t)v.y; o[2] = (bf16_t)v.z; o[3] = (bf16_t)v.w;
}

// ---------------------------------------------------------------------------
// T0: xs (b, c, hw) fp32 -> Xt (b, hw, c) bf16   [64x64 LDS tile transpose]
// ---------------------------------------------------------------------------
__global__ __launch_bounds__(256) void t0_kernel(const float* __restrict__ xs,
                                                 bf16_t* __restrict__ Xt) {
  __shared__ bf16_t T[64 * 72];                 // [hw][c], padded stride
  const int hw0 = blockIdx.x * 64, c0 = blockIdx.y * 64;
  const size_t boff = (size_t)blockIdx.z * CC * HWT;
  const int t = threadIdx.x;
  for (int p = 0; p < 4; p++) {
    int job = t + p * 256;                      // 1024 jobs: 64 c-rows x 16 float4
    int c_l = job >> 4, ch = job & 15;
    float4 v = *(const float4*)(xs + boff + (size_t)(c0 + c_l) * HWT + hw0 + ch * 4);
    T[(ch * 4 + 0) * 72 + c_l] = (bf16_t)v.x;
    T[(ch * 4 + 1) * 72 + c_l] = (bf16_t)v.y;
    T[(ch * 4 + 2) * 72 + c_l] = (bf16_t)v.z;
    T[(ch * 4 + 3) * 72 + c_l] = (bf16_t)v.w;
  }
  __syncthreads();
  for (int p = 0; p < 2; p++) {
    int job = t + p * 256;                      // 512 jobs: 64 hw-rows x 8 chunks
    int hw_l = job >> 3, ch = job & 7;
    uint4 v = *(const uint4*)&T[hw_l * 72 + ch * 8];
    *(uint4*)(Xt + boff + (size_t)(hw0 + hw_l) * CC + c0 + ch * 8) = v;
  }
}

// ---------------------------------------------------------------------------
// GEMM: D[b][m][n] = sum_k A[b][m][k] * Wt[n][k]   (all bf16)
//   A: (b, HWT, CC) token-major.  Wt: (N, CC) [n][k].  D: (b, HWT, ldD).
// BM=BN=128, BK=32; 4 waves 2x2; wave tile 64x64 = 4x4 mfma_16x16x32.
// m97 structure: global->LDS via global_load_lds width 16, unpadded LDS,
// 2 barriers per K-step.
// ---------------------------------------------------------------------------
__global__ __launch_bounds__(256) void gemm_kernel(const bf16_t* __restrict__ A,
                                                   const bf16_t* __restrict__ Wt,
                                                   bf16_t* __restrict__ D,
                                                   int ldD) {
  __shared__ bf16_t As[128 * 32];               // [row][k], UNPADDED (gload_lds)
  __shared__ bf16_t Ws[128 * 32];
  const int m0 = blockIdx.x * 128, n0 = blockIdx.y * 128;
  const bf16_t* Ab = A + (size_t)blockIdx.z * HWT * CC;
  bf16_t* Db = D + (size_t)blockIdx.z * HWT * (size_t)ldD;
  const int t = threadIdx.x;
  const int lane = t & 63, wv = t >> 6;
  const int wy = wv >> 1, wx = wv & 1;
  const int ln15 = lane & 15, q8 = (lane >> 4) * 8;

  // Staging geometry: tile = 8 KiB = 8 wave-segments of 1024 B (64 lanes x 16 B).
  // Wave wv owns segments {2wv, 2wv+1}. Lane covers row seg*16 + (lane>>2),
  // k-chunk (lane&3)*8 — exactly linear LDS order (HW scatters base+lane*16).
  const int seg0 = wv * 2;
  const int srow = lane >> 2;
  const int scol = (lane & 3) * 8;

  f32x4 acc[4][4];
  for (int i = 0; i < 4; i++)
    for (int j = 0; j < 4; j++) acc[i][j] = {0.f, 0.f, 0.f, 0.f};

  for (int kb = 0; kb < 16; kb++) {
    const int kk = kb * 32;
#pragma unroll
    for (int i = 0; i < 2; i++) {
      const int seg = seg0 + i;
      const int row = seg * 16 + srow;
      GLOAD_LDS16(Ab + (size_t)(m0 + row) * CC + kk + scol, &As[seg * 512]);
      GLOAD_LDS16(Wt + (size_t)(n0 + row) * CC + kk + scol, &Ws[seg * 512]);
    }
    __syncthreads();                            // drains vmcnt(0): tiles ready
    bf16x8 af[4], wf[4];
    for (int i = 0; i < 4; i++)
      af[i] = *(const bf16x8*)&As[(wy * 64 + i * 16 + ln15) * 32 + q8];
    for (int j = 0; j < 4; j++)
      wf[j] = *(const bf16x8*)&Ws[(wx * 64 + j * 16 + ln15) * 32 + q8];
    for (int i = 0; i < 4; i++)
      for (int j = 0; j < 4; j++)
        acc[i][j] = __builtin_amdgcn_mfma_f32_16x16x32_bf16(af[i], wf[j], acc[i][j], 0, 0, 0);
    __syncthreads();                            // all reads done before overwrite
  }

  const int qr = (lane >> 4) * 4;
  for (int i = 0; i < 4; i++)
    for (int j = 0; j < 4; j++) {
      const int row = m0 + wy * 64 + i * 16 + qr;
      const int col = n0 + wx * 64 + j * 16 + ln15;
      for (int r = 0; r < 4; r++)
        Db[(size_t)(row + r) * ldD + col] = (bf16_t)acc[i][j][r];
    }
}

// ---------------------------------------------------------------------------
// Attention: one block per (o, head, b). S=128, dh=64, full softmax.
//   QKV input token pitch = in strides (packed 1536); O output pitch = 512.
// ---------------------------------------------------------------------------
__global__ __launch_bounds__(256) void attn_kernel(const bf16_t* __restrict__ Q,
                                                   const bf16_t* __restrict__ K,
                                                   const bf16_t* __restrict__ V,
                                                   bf16_t* __restrict__ O,
                                                   int in_ss, int in_os, int in_bs,
                                                   int out_ss, int out_os, int out_bs) {
  __shared__ bf16_t smem[128 * 72 * 2 + 64 * 136];
  bf16_t* Qs = smem;                 // [128][72]
  bf16_t* Ks = smem + 128 * 72;      // [128][72]
  bf16_t* Vs = smem + 2 * 128 * 72;  // [64][136]  V^T: [d][s']
  bf16_t* Ps = smem;                 // [128][136] aliases Qs+Ks (dead after S)

  const int o = blockIdx.x, head = blockIdx.y;
  const size_t ibase = (size_t)blockIdx.z * in_bs + (size_t)o * in_os + head * 64;
  const size_t obase = (size_t)blockIdx.z * out_bs + (size_t)o * out_os + head * 64;
  const int t = threadIdx.x, lane = t & 63, wv = t >> 6;
  const int ln15 = lane & 15, q = lane >> 4;

  for (int p = 0; p < 4; p++) {
    int job = t + p * 256;
    int s = job >> 3, ch = job & 7;
    uint4 qv = *(const uint4*)(Q + ibase + (size_t)s * in_ss + ch * 8);
    uint4 kv = *(const uint4*)(K + ibase + (size_t)s * in_ss + ch * 8);
    *(uint4*)&Qs[s * 72 + ch * 8] = qv;
    *(uint4*)&Ks[s * 72 + ch * 8] = kv;
  }
  for (int p = 0; p < 4; p++) {
    int job = t + p * 256;
    int s = job >> 3, ch = job & 7;
    uint4 vv = *(const uint4*)(V + ibase + (size_t)s * in_ss + ch * 8);
    const bf16_t* e = (const bf16_t*)&vv;
    for (int jj = 0; jj < 8; jj++) Vs[(ch * 8 + jj) * 136 + s] = e[jj];
  }
  __syncthreads();

  // S = Q K^T
  f32x4 sacc[2][8];
  for (int i = 0; i < 2; i++)
    for (int j = 0; j < 8; j++) sacc[i][j] = {0.f, 0.f, 0.f, 0.f};
  for (int ks = 0; ks < 2; ks++) {
    bf16x8 qf[2], kf[8];
    for (int i = 0; i < 2; i++)
      qf[i] = *(const bf16x8*)&Qs[(wv * 32 + i * 16 + ln15) * 72 + ks * 32 + q * 8];
    for (int j = 0; j < 8; j++)
      kf[j] = *(const bf16x8*)&Ks[(j * 16 + ln15) * 72 + ks * 32 + q * 8];
    for (int i = 0; i < 2; i++)
      for (int j = 0; j < 8; j++)
        sacc[i][j] = __builtin_amdgcn_mfma_f32_16x16x32_bf16(qf[i], kf[j], sacc[i][j], 0, 0, 0);
  }
  __syncthreads();   // everyone done reading Qs/Ks (Ps aliases them)

  // Softmax per row (row lives in a 16-lane quad group)
  const float scale = 0.125f;
  float linv[2][4];
  for (int i = 0; i < 2; i++)
    for (int r = 0; r < 4; r++) {
      float m = -1e30f;
      for (int j = 0; j < 8; j++) m = fmaxf(m, sacc[i][j][r]);
      for (int d = 1; d < 16; d <<= 1) m = fmaxf(m, __shfl_xor(m, d));
      m *= scale;
      float sum = 0.f;
      for (int j = 0; j < 8; j++) {
        float pv = __expf(sacc[i][j][r] * scale - m);
        sacc[i][j][r] = pv;
        sum += pv;
      }
      for (int d = 1; d < 16; d <<= 1) sum += __shfl_xor(sum, d);
      linv[i][r] = 1.f / sum;
    }
  for (int i = 0; i < 2; i++)
    for (int j = 0; j < 8; j++)
      for (int r = 0; r < 4; r++)
        Ps[(wv * 32 + i * 16 + q * 4 + r) * 136 + j * 16 + ln15] = (bf16_t)sacc[i][j][r];
  __syncthreads();

  // O = P V
  f32x4 oacc[2][4];
  for (int i = 0; i < 2; i++)
    for (int j = 0; j < 4; j++) oacc[i][j] = {0.f, 0.f, 0.f, 0.f};
  for (int ks = 0; ks < 4; ks++) {
    bf16x8 pf[2], vf[4];
    for (int i = 0; i < 2; i++)
      pf[i] = *(const bf16x8*)&Ps[(wv * 32 + i * 16 + ln15) * 136 + ks * 32 + q * 8];
    for (int j = 0; j < 4; j++)
      vf[j] = *(const bf16x8*)&Vs[(j * 16 + ln15) * 136 + ks * 32 + q * 8];
    for (int i = 0; i < 2; i++)
      for (int j = 0; j < 4; j++)
        oacc[i][j] = __builtin_amdgcn_mfma_f32_16x16x32_bf16(pf[i], vf[j], oacc[i][j], 0, 0, 0);
  }
  for (int i = 0; i < 2; i++)
    for (int j = 0; j < 4; j++)
      for (int r = 0; r < 4; r++) {
        const int s = wv * 32 + i * 16 + q * 4 + r;
        const int d = j * 16 + ln15;
        O[obase + (size_t)s * out_ss + d] = (bf16_t)(oacc[i][j][r] * linv[i][r]);
      }
}

// ---------------------------------------------------------------------------
// FINAL: out (b,c,hw) fp32 = xs fp32 + OH bf16 (b,hw,c) + OW bf16 (b,hw,c)
// ---------------------------------------------------------------------------
__global__ __launch_bounds__(256) void final_add_kernel(const float* __restrict__ xs,
                                                        const bf16_t* __restrict__ OH,
                                                        const bf16_t* __restrict__ OW,
                                                        float* __restrict__ out) {
  __shared__ float TF[64 * 65];                 // [c][hw], +1 pad
  const int hw0 = blockIdx.x * 64, c0 = blockIdx.y * 64;
  const size_t boff = (size_t)blockIdx.z * CC * HWT;
  const int t = threadIdx.x;
  for (int p = 0; p < 2; p++) {
    int job = t + p * 256;                      // 64 hw-rows x 8 c-chunks
    int hw_l = job >> 3, ch = job & 7;
    size_t off = boff + (size_t)(hw0 + hw_l) * CC + c0 + ch * 8;
    bf16x8 a = *(const bf16x8*)(OH + off);
    bf16x8 b = *(const bf16x8*)(OW + off);
    for (int jj = 0; jj < 8; jj++)
      TF[(ch * 8 + jj) * 65 + hw_l] = (float)a[jj] + (float)b[jj];
  }
  __syncthreads();
  for (int p = 0; p < 4; p++) {
    int job = t + p * 256;                      // 64 c-rows x 16 float4 chunks
    int c_l = job >> 4, ch = job & 15;
    size_t off = boff + (size_t)(c0 + c_l) * HWT + hw0 + ch * 4;
    float4 xv = *(const float4*)(xs + off);
    float4 ov;
    ov.x = xv.x + TF[c_l * 65 + ch * 4 + 0];
    ov.y = xv.y + TF[c_l * 65 + ch * 4 + 1];
    ov.z = xv.z + TF[c_l * 65 + ch * 4 + 2];
    ov.w = xv.w + TF[c_l * 65 + ch * 4 + 3];
    *(float4*)(out + off) = ov;
  }
}

// ---------------------------------------------------------------------------
extern "C" void kernel_launch(void* const* d_in, const int* in_sizes, int n_in,
                              void* d_out, int out_size, void* d_ws, size_t ws_size,
                              hipStream_t stream) {
  const float* xs = (const float*)d_in[0];
  float* out = (float*)d_out;

  // Workspace carve-up: bf16 weights first, then 6 bf16 activation buffers.
  bf16_t* Wb = (bf16_t*)d_ws;                   // 8 * 512*512 bf16 = 4 MiB
  const size_t wbytes = (size_t)8 * CC * CC * sizeof(bf16_t);
  bf16_t* wsb = Wb + (size_t)8 * CC * CC;

  const size_t pb = (size_t)HWT * CC;           // elems per batch per buffer
  size_t avail = (ws_size > wbytes) ? (ws_size - wbytes) : 0;
  int chunkB = (int)(avail / (6 * pb * sizeof(bf16_t)));
  if (chunkB > NB) chunkB = NB;
  if (chunkB < 1) chunkB = 1;
  const size_t R = (size_t)chunkB * pb;
  bf16_t* Xt  = wsb;         // reused as OW buffer at the tail
  bf16_t* QKV = wsb + R;     // packed (b, hw, 1536): Q|K|V
  bf16_t* Ab  = wsb + 4 * R;
  bf16_t* OH  = wsb + 5 * R;

  // Convert weights to bf16: order q_h,k_h,v_h,o_h,q_w,k_w,v_w,o_w
  prep_w_kernel<<<dim3(CC * CC / 1024, 8), 256, 0, stream>>>(
      (const float*)d_in[1], (const float*)d_in[2], (const float*)d_in[3],
      (const float*)d_in[4], (const float*)d_in[5], (const float*)d_in[6],
      (const float*)d_in[7], (const float*)d_in[8], Wb);
  const bf16_t* Wqkv_h = Wb + 0 * (size_t)CC * CC;   // slots 0..2 packed (1536,512)
  const bf16_t* Wo_h   = Wb + 3 * (size_t)CC * CC;
  const bf16_t* Wqkv_w = Wb + 4 * (size_t)CC * CC;   // slots 4..6
  const bf16_t* Wo_w   = Wb + 7 * (size_t)CC * CC;

  for (int b0 = 0; b0 < NB; b0 += chunkB) {
    const int cb = (NB - b0 < chunkB) ? (NB - b0) : chunkB;
    const float* xsc = xs + (size_t)b0 * pb;
    float* outc = out + (size_t)b0 * pb;
    dim3 gT(HWT / 64, CC / 64, cb);
    dim3 gQKV(HWT / 128, C3 / 128, cb);
    dim3 gO(HWT / 128, CC / 128, cb);
    dim3 gA(128, 8, cb);
    dim3 blk(256);

    t0_kernel<<<gT, blk, 0, stream>>>(xsc, Xt);
    // height attention (seq along h: token stride 128*pitch; o pos along w)
    gemm_kernel<<<gQKV, blk, 0, stream>>>(Xt, Wqkv_h, QKV, C3);
    attn_kernel<<<gA, blk, 0, stream>>>(QKV, QKV + 512, QKV + 1024, Ab,
                                        128 * C3, C3, HWT * C3,
                                        128 * CC, CC, HWT * CC);
    gemm_kernel<<<gO, blk, 0, stream>>>(Ab, Wo_h, OH, CC);
    // width attention (seq along w: token stride pitch; o pos along h)
    gemm_kernel<<<gQKV, blk, 0, stream>>>(Xt, Wqkv_w, QKV, C3);
    attn_kernel<<<gA, blk, 0, stream>>>(QKV, QKV + 512, QKV + 1024, Ab,
                                        C3, 128 * C3, HWT * C3,
                                        CC, 128 * CC, HWT * CC);
    gemm_kernel<<<gO, blk, 0, stream>>>(Ab, Wo_w, Xt, CC);   // OW -> Xt (dead)
    final_add_kernel<<<gT, blk, 0, stream>>>(xsc, OH, Xt, outc);
  }
}

// Round 2
// 1626.793 us; speedup vs baseline: 1.0650x; 1.0016x over previous
//
#include <hip/hip_runtime.h>

// AxialAttentionBlock: xs (B=8, C=512, H=128, W=128) fp32, 8 heads, dh=64.
// I/O fp32 (per reference); internal compute bf16 MFMA.
// R2: GEMM -> 256x256 8-phase template (T2 swizzle + T3/T4 counted vmcnt + T5).
#define CC   512
#define HWT  16384     // H*W
#define NB   8         // batches
#define DH   64
#define SEQ  128
#define C3   1536      // packed QKV pitch

typedef __bf16 bf16_t;
typedef __bf16 bf16x8 __attribute__((ext_vector_type(8)));
typedef float  f32x4  __attribute__((ext_vector_type(4)));

#define GLOAD_LDS16(g, l)                                                      \
  __builtin_amdgcn_global_load_lds(                                            \
      (const __attribute__((address_space(1))) void*)(g),                      \
      (__attribute__((address_space(3))) void*)(l), 16, 0, 0)

#define WAITV4() asm volatile("s_waitcnt vmcnt(4)" ::: "memory")
#define WAITV0() asm volatile("s_waitcnt vmcnt(0)" ::: "memory")
#define LGKM0()  asm volatile("s_waitcnt lgkmcnt(0)" ::: "memory")
#define BARX()                                                                 \
  {                                                                            \
    asm volatile("" ::: "memory");                                             \
    __builtin_amdgcn_s_barrier();                                              \
    asm volatile("" ::: "memory");                                             \
  }
#define MFMA(d, x, y) d = __builtin_amdgcn_mfma_f32_16x16x32_bf16(x, y, d, 0, 0, 0)

// ---------------------------------------------------------------------------
// PREP: 8 weight matrices fp32 (C,C) -> bf16, layout unchanged ([n][k]).
// Slot order q_h,k_h,v_h,o_h,q_w,k_w,v_w,o_w: slots 0-2 / 4-6 form packed
// (1536,512) QKV weights.
// ---------------------------------------------------------------------------
__global__ __launch_bounds__(256) void prep_w_kernel(const float* __restrict__ W0,
                                                     const float* __restrict__ W1,
                                                     const float* __restrict__ W2,
                                                     const float* __restrict__ W3,
                                                     const float* __restrict__ W4,
                                                     const float* __restrict__ W5,
                                                     const float* __restrict__ W6,
                                                     const float* __restrict__ W7,
                                                     bf16_t* __restrict__ Wb) {
  const float* Wsrc[8] = {W0, W1, W2, W3, W4, W5, W6, W7};
  const int w = blockIdx.y;
  const int i = (blockIdx.x * 256 + threadIdx.x) * 4;      // 512*512 elems per W
  float4 v = *(const float4*)(Wsrc[w] + i);
  bf16_t* o = Wb + (size_t)w * (CC * CC) + i;
  o[0] = (bf16_t)v.x; o[1] = (bf16_t)v.y; o[2] = (bf16_t)v.z; o[3] = (bf16_t)v.w;
}

// ---------------------------------------------------------------------------
// T0: xs (b, c, hw) fp32 -> Xt (b, hw, c) bf16   [64x64 LDS tile transpose]
// ---------------------------------------------------------------------------
__global__ __launch_bounds__(256) void t0_kernel(const float* __restrict__ xs,
                                                 bf16_t* __restrict__ Xt) {
  __shared__ bf16_t T[64 * 72];                 // [hw][c], padded stride
  const int hw0 = blockIdx.x * 64, c0 = blockIdx.y * 64;
  const size_t boff = (size_t)blockIdx.z * CC * HWT;
  const int t = threadIdx.x;
  for (int p = 0; p < 4; p++) {
    int job = t + p * 256;                      // 1024 jobs: 64 c-rows x 16 float4
    int c_l = job >> 4, ch = job & 15;
    float4 v = *(const float4*)(xs + boff + (size_t)(c0 + c_l) * HWT + hw0 + ch * 4);
    T[(ch * 4 + 0) * 72 + c_l] = (bf16_t)v.x;
    T[(ch * 4 + 1) * 72 + c_l] = (bf16_t)v.y;
    T[(ch * 4 + 2) * 72 + c_l] = (bf16_t)v.z;
    T[(ch * 4 + 3) * 72 + c_l] = (bf16_t)v.w;
  }
  __syncthreads();
  for (int p = 0; p < 2; p++) {
    int job = t + p * 256;                      // 512 jobs: 64 hw-rows x 8 chunks
    int hw_l = job >> 3, ch = job & 7;
    uint4 v = *(const uint4*)&T[hw_l * 72 + ch * 8];
    *(uint4*)(Xt + boff + (size_t)(hw0 + hw_l) * CC + c0 + ch * 8) = v;
  }
}

// ---------------------------------------------------------------------------
// GEMM 256x256, BK=64, 8 waves (2Mx4N), double-buffered LDS, 8-phase schedule.
//   D[b][m][n] = sum_k A[b][m][k] * Wt[n][k]; A pitch CC, Wt pitch CC, D pitch ldD.
// LDS: As[2][256][64] | Bs[2][256][64] bf16 = 128 KiB. Swizzle: 16B-granule XOR
//   colE ^= ((row>>2)&3)<<3 applied on BOTH the gload source col and ds_read col
//   (linear LDS dest per global_load_lds constraint).
// Schedule (verified on paper): per iter (K-tiles kt0, kt0+1):
//   ph1 ds[A r0-3,B c0-1 buf0] stage A(kt0+1,0) | ph2 ds[B c2-3] stage A(kt0+1,1)
//   ph3 ds[A r4-7]            stage B(kt0+2,0) | ph4 stage B(kt0+2,1) vmcnt(4)
//   ph5-8 mirror on buf1, staging A(kt0+2,*), B(kt0+3,*), vmcnt(4) at ph8.
//   Every slot overwrite is >=1 barrier after its last reader; every consumer
//   covered by the preceding counted vmcnt. Last iter: stages off, vmcnt(0) @ph4.
// ---------------------------------------------------------------------------
__global__ __launch_bounds__(512, 2) void gemm256_kernel(const bf16_t* __restrict__ A,
                                                         const bf16_t* __restrict__ Wt,
                                                         bf16_t* __restrict__ D,
                                                         int ldD) {
  __shared__ bf16_t smem[65536];                // 128 KiB
  bf16_t* As = smem;                            // [2][256][64]
  bf16_t* Bs = smem + 32768;                    // [2][256][64]

  // XCD-chunked bijective remap (nwg2 = 64*gridDim.y, divisible by 8 here)
  const int flat = blockIdx.x + 64 * blockIdx.y;
  const int cpx = (64 * gridDim.y) >> 3;
  const int swz = (flat & 7) * cpx + (flat >> 3);
  const int m0 = (swz & 63) << 8;
  const int n0 = (swz >> 6) << 8;
  const bf16_t* Ab = A + (size_t)blockIdx.z * HWT * CC;
  bf16_t* Db = D + (size_t)blockIdx.z * HWT * (size_t)ldD;

  const int t = threadIdx.x;
  const int lane = t & 63, wv = t >> 6;
  const int wm = wv >> 2, wn = wv & 3;          // 2 x 4 wave grid
  const int ln15 = lane & 15, q8 = (lane >> 4) * 8;
  const int xr = ((ln15 >> 2) & 3) << 3;        // read-side swizzle (frag-invariant)
  const int cA = q8 ^ xr;                       // ks=0 col; ks=1 col = cA + 32
  // stage-side: thread t covers row r*64+(t>>3), linear col (t&7)*8, src col XORed
  const int srow = t >> 3;
  const int scol = ((t & 7) * 8) ^ (((t >> 5) & 3) << 3);

#define FRAGLD(dst, tile, row, ks)                                             \
  dst = *(const bf16x8*)((tile) + (row) * 64 + cA + (ks) * 32)

#define STAGE_HALF(src, ldsHalf)                                               \
  {                                                                            \
    GLOAD_LDS16((src) + (size_t)srow * CC + scol, (ldsHalf) + wv * 512);       \
    GLOAD_LDS16((src) + (size_t)(64 + srow) * CC + scol,                       \
                (ldsHalf) + 4096 + wv * 512);                                  \
  }
#define STAGE_A(kt, half)                                                      \
  STAGE_HALF(Ab + (size_t)(m0 + (half) * 128) * CC + (kt) * 64,                \
             As + ((kt) & 1) * 16384 + (half) * 8192)
#define STAGE_B(kt, half)                                                      \
  STAGE_HALF(Wt + (size_t)(n0 + (half) * 128) * CC + (kt) * 64,                \
             Bs + ((kt) & 1) * 16384 + (half) * 8192)

  f32x4 acc[8][4];
#pragma unroll
  for (int f = 0; f < 8; f++)
#pragma unroll
    for (int g = 0; g < 4; g++) acc[f][g] = {0.f, 0.f, 0.f, 0.f};
  bf16x8 a[4][2], b0[2][2], b1[2][2];

  // prologue: K0 (A+B) fully, B1; leave B1 (4 loads) in flight
  STAGE_A(0, 0); STAGE_A(0, 1);
  STAGE_B(0, 0); STAGE_B(0, 1);
  STAGE_B(1, 0); STAGE_B(1, 1);
  WAITV4();
  BARX();

#pragma unroll 1
  for (int i = 0; i < 4; i++) {
    const int kt0 = 2 * i;
    const bool last = (i == 3);
    const bf16_t* At0 = As;
    const bf16_t* Bt0 = Bs;
    const bf16_t* At1 = As + 16384;
    const bf16_t* Bt1 = Bs + 16384;

    // ===== ph1: ds A r0-3 + B c0-1 (buf0); stage A(kt0+1,0) =====
#pragma unroll
    for (int f = 0; f < 4; f++) {
      const int row = wm * 128 + f * 16 + ln15;
      FRAGLD(a[f][0], At0, row, 0);
      FRAGLD(a[f][1], At0, row, 1);
    }
#pragma unroll
    for (int g = 0; g < 2; g++) {
      const int row = wn * 64 + g * 16 + ln15;
      FRAGLD(b0[g][0], Bt0, row, 0);
      FRAGLD(b0[g][1], Bt0, row, 1);
    }
    STAGE_A(kt0 + 1, 0);
    BARX(); LGKM0();
    __builtin_amdgcn_s_setprio(1);
#pragma unroll
    for (int f = 0; f < 4; f++)
#pragma unroll
      for (int g = 0; g < 2; g++) {
        MFMA(acc[f][g], a[f][0], b0[g][0]);
        MFMA(acc[f][g], a[f][1], b0[g][1]);
      }
    __builtin_amdgcn_s_setprio(0);
    BARX();

    // ===== ph2: ds B c2-3; stage A(kt0+1,1) =====
#pragma unroll
    for (int g = 0; g < 2; g++) {
      const int row = wn * 64 + (g + 2) * 16 + ln15;
      FRAGLD(b1[g][0], Bt0, row, 0);
      FRAGLD(b1[g][1], Bt0, row, 1);
    }
    STAGE_A(kt0 + 1, 1);
    BARX(); LGKM0();
    __builtin_amdgcn_s_setprio(1);
#pragma unroll
    for (int f = 0; f < 4; f++)
#pragma unroll
      for (int g = 0; g < 2; g++) {
        MFMA(acc[f][g + 2], a[f][0], b1[g][0]);
        MFMA(acc[f][g + 2], a[f][1], b1[g][1]);
      }
    __builtin_amdgcn_s_setprio(0);
    BARX();

    // ===== ph3: ds A r4-7; stage B(kt0+2,0) =====
#pragma unroll
    for (int f = 0; f < 4; f++) {
      const int row = wm * 128 + (f + 4) * 16 + ln15;
      FRAGLD(a[f][0], At0, row, 0);
      FRAGLD(a[f][1], At0, row, 1);
    }
    if (!last) STAGE_B(kt0 + 2, 0);
    BARX(); LGKM0();
    __builtin_amdgcn_s_setprio(1);
#pragma unroll
    for (int f = 0; f < 4; f++)
#pragma unroll
      for (int g = 0; g < 2; g++) {
        MFMA(acc[f + 4][g + 2], a[f][0], b1[g][0]);
        MFMA(acc[f + 4][g + 2], a[f][1], b1[g][1]);
      }
    __builtin_amdgcn_s_setprio(0);
    BARX();

    // ===== ph4: stage B(kt0+2,1); counted vmcnt; MFMA r4-7 x c0-1 =====
    if (!last) {
      STAGE_B(kt0 + 2, 1);
      WAITV4();               // A(kt0+1) + B(kt0+1) guaranteed landed
    } else {
      WAITV0();               // last iter: drain so ph5-8 can read K7
    }
    BARX();
    __builtin_amdgcn_s_setprio(1);
#pragma unroll
    for (int f = 0; f < 4; f++)
#pragma unroll
      for (int g = 0; g < 2; g++) {
        MFMA(acc[f + 4][g], a[f][0], b0[g][0]);
        MFMA(acc[f + 4][g], a[f][1], b0[g][1]);
      }
    __builtin_amdgcn_s_setprio(0);
    BARX();

    // ===== ph5: ds A' r0-3 + B' c0-1 (buf1); stage A(kt0+2,0) =====
#pragma unroll
    for (int f = 0; f < 4; f++) {
      const int row = wm * 128 + f * 16 + ln15;
      FRAGLD(a[f][0], At1, row, 0);
      FRAGLD(a[f][1], At1, row, 1);
    }
#pragma unroll
    for (int g = 0; g < 2; g++) {
      const int row = wn * 64 + g * 16 + ln15;
      FRAGLD(b0[g][0], Bt1, row, 0);
      FRAGLD(b0[g][1], Bt1, row, 1);
    }
    if (!last) STAGE_A(kt0 + 2, 0);
    BARX(); LGKM0();
    __builtin_amdgcn_s_setprio(1);
#pragma unroll
    for (int f = 0; f < 4; f++)
#pragma unroll
      for (int g = 0; g < 2; g++) {
        MFMA(acc[f][g], a[f][0], b0[g][0]);
        MFMA(acc[f][g], a[f][1], b0[g][1]);
      }
    __builtin_amdgcn_s_setprio(0);
    BARX();

    // ===== ph6: ds B' c2-3; stage A(kt0+2,1) =====
#pragma unroll
    for (int g = 0; g < 2; g++) {
      const int row = wn * 64 + (g + 2) * 16 + ln15;
      FRAGLD(b1[g][0], Bt1, row, 0);
      FRAGLD(b1[g][1], Bt1, row, 1);
    }
    if (!last) STAGE_A(kt0 + 2, 1);
    BARX(); LGKM0();
    __builtin_amdgcn_s_setprio(1);
#pragma unroll
    for (int f = 0; f < 4; f++)
#pragma unroll
      for (int g = 0; g < 2; g++) {
        MFMA(acc[f][g + 2], a[f][0], b1[g][0]);
        MFMA(acc[f][g + 2], a[f][1], b1[g][1]);
      }
    __builtin_amdgcn_s_setprio(0);
    BARX();

    // ===== ph7: ds A' r4-7; stage B(kt0+3,0) =====
#pragma unroll
    for (int f = 0; f < 4; f++) {
      const int row = wm * 128 + (f + 4) * 16 + ln15;
      FRAGLD(a[f][0], At1, row, 0);
      FRAGLD(a[f][1], At1, row, 1);
    }
    if (!last) STAGE_B(kt0 + 3, 0);
    BARX(); LGKM0();
    __builtin_amdgcn_s_setprio(1);
#pragma unroll
    for (int f = 0; f < 4; f++)
#pragma unroll
      for (int g = 0; g < 2; g++) {
        MFMA(acc[f + 4][g + 2], a[f][0], b1[g][0]);
        MFMA(acc[f + 4][g + 2], a[f][1], b1[g][1]);
      }
    __builtin_amdgcn_s_setprio(0);
    BARX();

    // ===== ph8: stage B(kt0+3,1); counted vmcnt; MFMA r4-7 x c0-1 =====
    if (!last) {
      STAGE_B(kt0 + 3, 1);
      WAITV4();               // A(kt0+2) + B(kt0+2) guaranteed for next ph1
    }
    BARX();
    __builtin_amdgcn_s_setprio(1);
#pragma unroll
    for (int f = 0; f < 4; f++)
#pragma unroll
      for (int g = 0; g < 2; g++) {
        MFMA(acc[f + 4][g], a[f][0], b0[g][0]);
        MFMA(acc[f + 4][g], a[f][1], b0[g][1]);
      }
    __builtin_amdgcn_s_setprio(0);
    BARX();
  }

  // epilogue
  const int qr = (lane >> 4) * 4;
  const int crow = m0 + wm * 128;
  const int ccol = n0 + wn * 64;
#pragma unroll
  for (int f = 0; f < 8; f++)
#pragma unroll
    for (int g = 0; g < 4; g++) {
      const int row = crow + f * 16 + qr;
      const int col = ccol + g * 16 + ln15;
#pragma unroll
      for (int r = 0; r < 4; r++)
        Db[(size_t)(row + r) * ldD + col] = (bf16_t)acc[f][g][r];
    }
#undef FRAGLD
#undef STAGE_HALF
#undef STAGE_A
#undef STAGE_B
}

// ---------------------------------------------------------------------------
// Attention: one block per (o, head, b). S=128, dh=64, full softmax.
//   QKV input token pitch = in strides (packed 1536); O output pitch = 512.
// ---------------------------------------------------------------------------
__global__ __launch_bounds__(256) void attn_kernel(const bf16_t* __restrict__ Q,
                                                   const bf16_t* __restrict__ K,
                                                   const bf16_t* __restrict__ V,
                                                   bf16_t* __restrict__ O,
                                                   int in_ss, int in_os, int in_bs,
                                                   int out_ss, int out_os, int out_bs) {
  __shared__ bf16_t smem[128 * 72 * 2 + 64 * 136];
  bf16_t* Qs = smem;                 // [128][72]
  bf16_t* Ks = smem + 128 * 72;      // [128][72]
  bf16_t* Vs = smem + 2 * 128 * 72;  // [64][136]  V^T: [d][s']
  bf16_t* Ps = smem;                 // [128][136] aliases Qs+Ks (dead after S)

  const int o = blockIdx.x, head = blockIdx.y;
  const size_t ibase = (size_t)blockIdx.z * in_bs + (size_t)o * in_os + head * 64;
  const size_t obase = (size_t)blockIdx.z * out_bs + (size_t)o * out_os + head * 64;
  const int t = threadIdx.x, lane = t & 63, wv = t >> 6;
  const int ln15 = lane & 15, q = lane >> 4;

  for (int p = 0; p < 4; p++) {
    int job = t + p * 256;
    int s = job >> 3, ch = job & 7;
    uint4 qv = *(const uint4*)(Q + ibase + (size_t)s * in_ss + ch * 8);
    uint4 kv = *(const uint4*)(K + ibase + (size_t)s * in_ss + ch * 8);
    *(uint4*)&Qs[s * 72 + ch * 8] = qv;
    *(uint4*)&Ks[s * 72 + ch * 8] = kv;
  }
  for (int p = 0; p < 4; p++) {
    int job = t + p * 256;
    int s = job >> 3, ch = job & 7;
    uint4 vv = *(const uint4*)(V + ibase + (size_t)s * in_ss + ch * 8);
    const bf16_t* e = (const bf16_t*)&vv;
    for (int jj = 0; jj < 8; jj++) Vs[(ch * 8 + jj) * 136 + s] = e[jj];
  }
  __syncthreads();

  // S = Q K^T
  f32x4 sacc[2][8];
  for (int i = 0; i < 2; i++)
    for (int j = 0; j < 8; j++) sacc[i][j] = {0.f, 0.f, 0.f, 0.f};
  for (int ks = 0; ks < 2; ks++) {
    bf16x8 qf[2], kf[8];
    for (int i = 0; i < 2; i++)
      qf[i] = *(const bf16x8*)&Qs[(wv * 32 + i * 16 + ln15) * 72 + ks * 32 + q * 8];
    for (int j = 0; j < 8; j++)
      kf[j] = *(const bf16x8*)&Ks[(j * 16 + ln15) * 72 + ks * 32 + q * 8];
    for (int i = 0; i < 2; i++)
      for (int j = 0; j < 8; j++)
        sacc[i][j] = __builtin_amdgcn_mfma_f32_16x16x32_bf16(qf[i], kf[j], sacc[i][j], 0, 0, 0);
  }
  __syncthreads();   // everyone done reading Qs/Ks (Ps aliases them)

  // Softmax per row (row lives in a 16-lane quad group)
  const float scale = 0.125f;
  float linv[2][4];
  for (int i = 0; i < 2; i++)
    for (int r = 0; r < 4; r++) {
      float m = -1e30f;
      for (int j = 0; j < 8; j++) m = fmaxf(m, sacc[i][j][r]);
      for (int d = 1; d < 16; d <<= 1) m = fmaxf(m, __shfl_xor(m, d));
      m *= scale;
      float sum = 0.f;
      for (int j = 0; j < 8; j++) {
        float pv = __expf(sacc[i][j][r] * scale - m);
        sacc[i][j][r] = pv;
        sum += pv;
      }
      for (int d = 1; d < 16; d <<= 1) sum += __shfl_xor(sum, d);
      linv[i][r] = 1.f / sum;
    }
  for (int i = 0; i < 2; i++)
    for (int j = 0; j < 8; j++)
      for (int r = 0; r < 4; r++)
        Ps[(wv * 32 + i * 16 + q * 4 + r) * 136 + j * 16 + ln15] = (bf16_t)sacc[i][j][r];
  __syncthreads();

  // O = P V
  f32x4 oacc[2][4];
  for (int i = 0; i < 2; i++)
    for (int j = 0; j < 4; j++) oacc[i][j] = {0.f, 0.f, 0.f, 0.f};
  for (int ks = 0; ks < 4; ks++) {
    bf16x8 pf[2], vf[4];
    for (int i = 0; i < 2; i++)
      pf[i] = *(const bf16x8*)&Ps[(wv * 32 + i * 16 + ln15) * 136 + ks * 32 + q * 8];
    for (int j = 0; j < 4; j++)
      vf[j] = *(const bf16x8*)&Vs[(j * 16 + ln15) * 136 + ks * 32 + q * 8];
    for (int i = 0; i < 2; i++)
      for (int j = 0; j < 4; j++)
        oacc[i][j] = __builtin_amdgcn_mfma_f32_16x16x32_bf16(pf[i], vf[j], oacc[i][j], 0, 0, 0);
  }
  for (int i = 0; i < 2; i++)
    for (int j = 0; j < 4; j++)
      for (int r = 0; r < 4; r++) {
        const int s = wv * 32 + i * 16 + q * 4 + r;
        const int d = j * 16 + ln15;
        O[obase + (size_t)s * out_ss + d] = (bf16_t)(oacc[i][j][r] * linv[i][r]);
      }
}

// ---------------------------------------------------------------------------
// FINAL: out (b,c,hw) fp32 = xs fp32 + OH bf16 (b,hw,c) + OW bf16 (b,hw,c)
// ---------------------------------------------------------------------------
__global__ __launch_bounds__(256) void final_add_kernel(const float* __restrict__ xs,
                                                        const bf16_t* __restrict__ OH,
                                                        const bf16_t* __restrict__ OW,
                                                        float* __restrict__ out) {
  __shared__ float TF[64 * 65];                 // [c][hw], +1 pad
  const int hw0 = blockIdx.x * 64, c0 = blockIdx.y * 64;
  const size_t boff = (size_t)blockIdx.z * CC * HWT;
  const int t = threadIdx.x;
  for (int p = 0; p < 2; p++) {
    int job = t + p * 256;                      // 64 hw-rows x 8 c-chunks
    int hw_l = job >> 3, ch = job & 7;
    size_t off = boff + (size_t)(hw0 + hw_l) * CC + c0 + ch * 8;
    bf16x8 a = *(const bf16x8*)(OH + off);
    bf16x8 b = *(const bf16x8*)(OW + off);
    for (int jj = 0; jj < 8; jj++)
      TF[(ch * 8 + jj) * 65 + hw_l] = (float)a[jj] + (float)b[jj];
  }
  __syncthreads();
  for (int p = 0; p < 4; p++) {
    int job = t + p * 256;                      // 64 c-rows x 16 float4 chunks
    int c_l = job >> 4, ch = job & 15;
    size_t off = boff + (size_t)(c0 + c_l) * HWT + hw0 + ch * 4;
    float4 xv = *(const float4*)(xs + off);
    float4 ov;
    ov.x = xv.x + TF[c_l * 65 + ch * 4 + 0];
    ov.y = xv.y + TF[c_l * 65 + ch * 4 + 1];
    ov.z = xv.z + TF[c_l * 65 + ch * 4 + 2];
    ov.w = xv.w + TF[c_l * 65 + ch * 4 + 3];
    *(float4*)(out + off) = ov;
  }
}

// ---------------------------------------------------------------------------
extern "C" void kernel_launch(void* const* d_in, const int* in_sizes, int n_in,
                              void* d_out, int out_size, void* d_ws, size_t ws_size,
                              hipStream_t stream) {
  const float* xs = (const float*)d_in[0];
  float* out = (float*)d_out;

  // Workspace carve-up: bf16 weights first, then 6 bf16 activation buffers.
  bf16_t* Wb = (bf16_t*)d_ws;                   // 8 * 512*512 bf16 = 4 MiB
  const size_t wbytes = (size_t)8 * CC * CC * sizeof(bf16_t);
  bf16_t* wsb = Wb + (size_t)8 * CC * CC;

  const size_t pb = (size_t)HWT * CC;           // elems per batch per buffer
  size_t avail = (ws_size > wbytes) ? (ws_size - wbytes) : 0;
  int chunkB = (int)(avail / (6 * pb * sizeof(bf16_t)));
  if (chunkB > NB) chunkB = NB;
  if (chunkB < 1) chunkB = 1;
  const size_t R = (size_t)chunkB * pb;
  bf16_t* Xt  = wsb;         // reused as OW buffer at the tail
  bf16_t* QKV = wsb + R;     // packed (b, hw, 1536): Q|K|V
  bf16_t* Ab  = wsb + 4 * R;
  bf16_t* OH  = wsb + 5 * R;

  // Convert weights to bf16: order q_h,k_h,v_h,o_h,q_w,k_w,v_w,o_w
  prep_w_kernel<<<dim3(CC * CC / 1024, 8), 256, 0, stream>>>(
      (const float*)d_in[1], (const float*)d_in[2], (const float*)d_in[3],
      (const float*)d_in[4], (const float*)d_in[5], (const float*)d_in[6],
      (const float*)d_in[7], (const float*)d_in[8], Wb);
  const bf16_t* Wqkv_h = Wb + 0 * (size_t)CC * CC;   // slots 0..2 packed (1536,512)
  const bf16_t* Wo_h   = Wb + 3 * (size_t)CC * CC;
  const bf16_t* Wqkv_w = Wb + 4 * (size_t)CC * CC;   // slots 4..6
  const bf16_t* Wo_w   = Wb + 7 * (size_t)CC * CC;

  for (int b0 = 0; b0 < NB; b0 += chunkB) {
    const int cb = (NB - b0 < chunkB) ? (NB - b0) : chunkB;
    const float* xsc = xs + (size_t)b0 * pb;
    float* outc = out + (size_t)b0 * pb;
    dim3 gT(HWT / 64, CC / 64, cb);
    dim3 gQKV(HWT / 256, C3 / 256, cb);       // (64, 6, cb)
    dim3 gO(HWT / 256, CC / 256, cb);         // (64, 2, cb)
    dim3 gA(128, 8, cb);
    dim3 blk(256), blk5(512);

    t0_kernel<<<gT, blk, 0, stream>>>(xsc, Xt);
    // height attention (seq along h: token stride 128*pitch; o pos along w)
    gemm256_kernel<<<gQKV, blk5, 0, stream>>>(Xt, Wqkv_h, QKV, C3);
    attn_kernel<<<gA, blk, 0, stream>>>(QKV, QKV + 512, QKV + 1024, Ab,
                                        128 * C3, C3, HWT * C3,
                                        128 * CC, CC, HWT * CC);
    gemm256_kernel<<<gO, blk5, 0, stream>>>(Ab, Wo_h, OH, CC);
    // width attention (seq along w: token stride pitch; o pos along h)
    gemm256_kernel<<<gQKV, blk5, 0, stream>>>(Xt, Wqkv_w, QKV, C3);
    attn_kernel<<<gA, blk, 0, stream>>>(QKV, QKV + 512, QKV + 1024, Ab,
                                        C3, 128 * C3, HWT * C3,
                                        CC, 128 * CC, HWT * CC);
    gemm256_kernel<<<gO, blk5, 0, stream>>>(Ab, Wo_w, Xt, CC);   // OW -> Xt (dead)
    final_add_kernel<<<gT, blk, 0, stream>>>(xsc, OH, Xt, outc);
  }
}